// Round 5
// baseline (234.616 us; speedup 1.0000x reference)
//
#include <hip/hip_runtime.h>
#include <hip/hip_bf16.h>
#include <math.h>

// AttnBlock: B=16, C=256, H=W=64, heads=4, dim_head=32
#define BATCH 16
#define CH 256
#define NPOS 4096
#define INNER 128
#define HEADS 4
#define DH 32

typedef __hip_bfloat16 bf16;
typedef short bf8v __attribute__((ext_vector_type(8)));    // 8 bf16 (4 VGPRs)
typedef float f32x4 __attribute__((ext_vector_type(4)));

__device__ __forceinline__ float b2f(bf16 v) { return __bfloat162float(v); }
__device__ __forceinline__ float us2f(unsigned short u) {
    unsigned w = ((unsigned)u) << 16; float f; __builtin_memcpy(&f, &w, 4); return f;
}
__device__ __forceinline__ unsigned short f2us(float f) {
    bf16 h = __float2bfloat16(f); unsigned short u; __builtin_memcpy(&u, &h, 2); return u;
}
__device__ __forceinline__ bf16 f2b(float v) { return __float2bfloat16(v); }
// async global->LDS, 16B/lane; LDS dest = wave-uniform base + lane*16
__device__ __forceinline__ void gload16(const void* g, void* l) {
    __builtin_amdgcn_global_load_lds(
        (__attribute__((address_space(1))) unsigned int*)(g),
        (__attribute__((address_space(3))) unsigned int*)(l), 16, 0, 0);
}

// ---------------------------------------------------------------------------
// K0: Wqkv fp32 -> bf16 once (keeps cvt + fp32 streaming out of K1's hot loop)
// ---------------------------------------------------------------------------
__global__ __launch_bounds__(256)
void convert_wq_kernel(const float* __restrict__ W, bf16* __restrict__ wq) {
    int i = blockIdx.x * 256 + threadIdx.x;     // 24576 float4 chunks
    float4 w = ((const float4*)W)[i];
    ushort4 o;
    o.x = f2us(w.x); o.y = f2us(w.y); o.z = f2us(w.z); o.w = f2us(w.w);
    ((ushort4*)wq)[i] = o;
}

// ---------------------------------------------------------------------------
// K1: fused LN + qkv GEMM + q-softmax. 512 threads (8 waves: 2m x 4n),
// grid (32 n-tiles, 16 b). A = LN(x)^T [128n][256c] bf16, LDS-resident
// (pad 264 -> 528B rows). 3 col-phases (k,v,q); B chunks [128][32] staged
// via global_load_lds from preconverted bf16 weights.
// LDS: A 67584 + Bb 8448 + stats 4096 = 80128 <= 81920 -> 2 blocks/CU.
// ---------------------------------------------------------------------------
__global__ __launch_bounds__(512)
void fused_qkv_kernel(const float* __restrict__ x, const bf16* __restrict__ wq,
                      bf16* __restrict__ p, bf16* __restrict__ kvt) {
    __shared__ bf16 A[128 * 264];      // 67584 B
    __shared__ bf16 Bb[32 * 132];      // 8448 B: B chunk [128][32] / kv dump [32][132]
    __shared__ float stats[1024];      // 4096 B

    const int b = blockIdx.y, n0 = blockIdx.x * 128;
    const int tid = threadIdx.x;
    const int wave = tid >> 6, lane = tid & 63;
    const int wm = (wave >> 2) * 64, wn = (wave & 3) * 32;
    const int lrow = lane & 15, kq = lane >> 4;

    // ---- stage x tile (raw bf16) + per-thread LN partials ----
    {
        const int n = tid & 127, cq = tid >> 7;      // 4 groups of 64 channels
        const float* xp = x + ((size_t)b * CH + cq * 64) * NPOS + n0 + n;
        float s = 0.f, sq = 0.f;
        for (int i0 = 0; i0 < 64; i0 += 8) {
            bf8v bv;
            #pragma unroll
            for (int j = 0; j < 8; ++j) {
                float v = xp[(size_t)(i0 + j) * NPOS];
                s += v; sq += v * v;
                bv[j] = (short)f2us(v);
            }
            *(bf8v*)&A[n * 264 + cq * 64 + i0] = bv;
        }
        stats[tid * 2] = s; stats[tid * 2 + 1] = sq;
    }
    __syncthreads();
    if (tid < 128) {        // slot tid only read by thread tid -> no race
        float s = 0.f, sq = 0.f;
        #pragma unroll
        for (int j = 0; j < 4; ++j) {
            s  += stats[(tid + 128 * j) * 2];
            sq += stats[(tid + 128 * j) * 2 + 1];
        }
        float m = s * (1.f / 256.f);
        float var = sq * (1.f / 256.f) - m * m;
        stats[tid * 2] = m;
        stats[tid * 2 + 1] = rsqrtf(var + 1e-5f);
    }
    __syncthreads();
    // ---- normalize A in place (u32 pairs) ----
    {
        unsigned* A32 = (unsigned*)A;       // row stride 132 u32
        #pragma unroll 4
        for (int i = 0; i < 32; ++i) {
            int idx = i * 512 + tid;
            int c2 = idx & 127, n = idx >> 7;
            unsigned u = A32[n * 132 + c2];
            float m = stats[n * 2], rs = stats[n * 2 + 1];
            float v0 = (us2f((unsigned short)(u & 0xffffu)) - m) * rs;
            float v1 = (us2f((unsigned short)(u >> 16)) - m) * rs;
            A32[n * 132 + c2] = (unsigned)f2us(v0) | ((unsigned)f2us(v1) << 16);
        }
    }

    for (int ph = 0; ph < 3; ++ph) {
        const int colbase = (ph == 2) ? 0 : (ph + 1) * 128;   // k, v, q
        f32x4 acc[4][2];
        #pragma unroll
        for (int i = 0; i < 4; ++i)
            #pragma unroll
            for (int j = 0; j < 2; ++j) acc[i][j] = (f32x4){0.f, 0.f, 0.f, 0.f};

        const int gcol = colbase + (tid >> 2), gq4 = tid & 3;
        for (int k0 = 0; k0 < 256; k0 += 32) {
            __syncthreads();   // Bb free (prev frag reads / epilogue done)
            gload16(wq + (size_t)gcol * 256 + k0 + gq4 * 8, (char*)Bb + wave * 1024);
            __syncthreads();   // drains vmcnt -> chunk visible
            bf8v af[4], bfr[2];
            #pragma unroll
            for (int t = 0; t < 4; ++t)
                af[t] = *(const bf8v*)&A[(wm + t * 16 + lrow) * 264 + k0 + kq * 8];
            #pragma unroll
            for (int t = 0; t < 2; ++t)
                bfr[t] = *(const bf8v*)&Bb[(wn + t * 16 + lrow) * 32 + kq * 8];
            #pragma unroll
            for (int mt = 0; mt < 4; ++mt)
                #pragma unroll
                for (int nt = 0; nt < 2; ++nt)
                    acc[mt][nt] = __builtin_amdgcn_mfma_f32_16x16x32_bf16(
                        af[mt], bfr[nt], acc[mt][nt], 0, 0, 0);
        }

        if (ph < 2) {
            // k/v epilogue: 4 passes of 32 rows via Bb [32][132] for coalesced stores
            unsigned* B32 = (unsigned*)Bb;           // row stride 66 u32
            unsigned* kv32 = (unsigned*)kvt;
            for (int pr = 0; pr < 4; ++pr) {
                __syncthreads();
                if ((wave >> 2) == (pr >> 1)) {
                    int mtb = (pr & 1) * 2;
                    #pragma unroll
                    for (int mi = 0; mi < 2; ++mi) {
                        int mt = mtb + mi;
                        #pragma unroll
                        for (int nt = 0; nt < 2; ++nt)
                            #pragma unroll
                            for (int r = 0; r < 4; ++r) {
                                int rl = mi * 16 + kq * 4 + r;       // 0..31
                                Bb[rl * 132 + wn + nt * 16 + lrow] = f2b(acc[mt][nt][r]);
                            }
                    }
                }
                __syncthreads();
                #pragma unroll
                for (int i = 0; i < 4; ++i) {
                    int idx = i * 512 + tid;     // 2048 u32
                    int c2 = idx & 63, rl = idx >> 6;
                    kv32[(size_t)(b * NPOS + n0 + pr * 32 + rl) * 128 + ph * 64 + c2] =
                        B32[rl * 66 + c2];
                }
            }
        } else {
            // q epilogue: dump accs over A (dead), softmax per (row, head), store p
            __syncthreads();
            bf16* pt = A;                        // [128][132]
            #pragma unroll
            for (int mt = 0; mt < 4; ++mt)
                #pragma unroll
                for (int nt = 0; nt < 2; ++nt)
                    #pragma unroll
                    for (int r = 0; r < 4; ++r)
                        pt[(wm + mt * 16 + kq * 4 + r) * 132 + wn + nt * 16 + lrow] =
                            f2b(acc[mt][nt][r]);
            __syncthreads();
            {   // reciprocal denominators (no max-sub: |q| small -> exp safe in fp32)
                int row = tid >> 2, h = tid & 3;
                float s = 0.f;
                #pragma unroll 8
                for (int j = 0; j < 32; ++j) s += __expf(b2f(pt[row * 132 + h * 32 + j]));
                stats[row * 4 + h] = 1.f / s;    // LN stats dead by now
            }
            __syncthreads();
            unsigned* pt32 = (unsigned*)pt;
            unsigned* pg32 = (unsigned*)p;
            #pragma unroll 4
            for (int i = 0; i < 16; ++i) {
                int idx = i * 512 + tid;         // 8192 u32
                int c2 = idx & 63, n = idx >> 6;
                unsigned u = pt32[n * 66 + c2];
                float rd = stats[n * 4 + (c2 >> 4)];
                float v0 = __expf(us2f((unsigned short)(u & 0xffffu))) * rd;
                float v1 = __expf(us2f((unsigned short)(u >> 16))) * rd;
                pg32[(size_t)(b * NPOS + n0 + n) * 64 + c2] =
                    (unsigned)f2us(v0) | ((unsigned)f2us(v1) << 16);
            }
        }
    }
}

// ---------------------------------------------------------------------------
// K2: context + wmod fused (wmod is head-separable). grid (4 h, 16 b),
// 512 threads. Per block: full-N context for one (b,h), then
// wmod[c][h,d] = (sum_e Wout[c][h*32+e]*cs[d][e]) / ses[d] / (N*sqrt(32)).
// ---------------------------------------------------------------------------
__global__ __launch_bounds__(512)
void context_wmod_kernel(const bf16* __restrict__ kvt, const float* __restrict__ Wout,
                         bf16* __restrict__ wmod) {
    __shared__ float kvbuf[2][128][36];   // ks=exp(k), vs; reduction overlay
    __shared__ float sep[4][32];
    __shared__ float ses[32];
    __shared__ float cs[1024];            // final [d][e]
    float (*ks)[36] = kvbuf[0];
    float (*vs)[36] = kvbuf[1];
    float* red = &kvbuf[0][0][0];         // 9216 floats >= 8192

    const int h = blockIdx.x, b = blockIdx.y;
    const int tid = threadIdx.x;
    const int wave = tid >> 6, lane = tid & 63;
    const int eg = lane & 7, dg = lane >> 3;
    const int sd = tid & 31, sq = (tid >> 5) & 3;
    const int koff = h * DH, voff = 128 + h * DH;
    const size_t rowbase = (size_t)b * NPOS * 256;

    float acc[4][4] = {};
    float se_loc = 0.f;

    for (int nc = 0; nc < NPOS; nc += 128) {
        for (int t = tid; t < 1024; t += 512) {
            int n = t >> 3, dq = t & 7;
            const bf16* row = kvt + rowbase + (size_t)(nc + n) * 256;
            ushort4 ku = *(const ushort4*)(row + koff + dq * 4);
            ushort4 vu = *(const ushort4*)(row + voff + dq * 4);
            f32x4 kf, vf;
            kf[0] = __expf(us2f(ku.x)); kf[1] = __expf(us2f(ku.y));
            kf[2] = __expf(us2f(ku.z)); kf[3] = __expf(us2f(ku.w));
            vf[0] = us2f(vu.x); vf[1] = us2f(vu.y); vf[2] = us2f(vu.z); vf[3] = us2f(vu.w);
            *(f32x4*)&ks[n][dq * 4] = kf;
            *(f32x4*)&vs[n][dq * 4] = vf;
        }
        __syncthreads();
        #pragma unroll 4
        for (int i = 0; i < 16; ++i) {
            int n = wave * 16 + i;
            f32x4 kv = *(const f32x4*)&ks[n][dg * 4];
            f32x4 vv = *(const f32x4*)&vs[n][eg * 4];
            #pragma unroll
            for (int j = 0; j < 4; ++j)
                #pragma unroll
                for (int i2 = 0; i2 < 4; ++i2)
                    acc[j][i2] += kv[j] * vv[i2];
        }
        if (tid < 128) {
            float s = 0.f;
            #pragma unroll 8
            for (int i = 0; i < 32; ++i) s += ks[sq * 32 + i][sd];
            se_loc += s;
        }
        __syncthreads();
    }

    if (tid < 128) sep[sq][sd] = se_loc;
    __syncthreads();      // all ks/vs reads done before red overlay
    #pragma unroll
    for (int j = 0; j < 4; ++j)
        #pragma unroll
        for (int i = 0; i < 4; ++i)
            red[(wave * 64 + lane) * 16 + j * 4 + i] = acc[j][i];
    __syncthreads();
    if (tid < 32) ses[tid] = sep[0][tid] + sep[1][tid] + sep[2][tid] + sep[3][tid];
    for (int t = tid; t < 1024; t += 512) {
        int d = t >> 5, e = t & 31;
        int l = (d >> 2) * 8 + (e >> 2);
        int slot = (d & 3) * 4 + (e & 3);
        float s = 0.f;
        #pragma unroll
        for (int w = 0; w < 8; ++w) s += red[(w * 64 + l) * 16 + slot];
        cs[t] = s;
    }
    __syncthreads();

    // wmod: thread -> (c = tid>>1, 16 d's)
    const int c = tid >> 1, d0 = (tid & 1) * 16;
    const float* wr = Wout + (size_t)c * INNER + h * DH;
    float w[32];
    #pragma unroll
    for (int i = 0; i < 8; ++i) {
        float4 t = *(const float4*)&wr[i * 4];
        w[i * 4] = t.x; w[i * 4 + 1] = t.y; w[i * 4 + 2] = t.z; w[i * 4 + 3] = t.w;
    }
    const float SCALE = 4.3158341e-05f;   // 1/(4096*sqrt(32))
    float val[16];
    #pragma unroll
    for (int dd = 0; dd < 16; ++dd) {
        int d = d0 + dd;
        const float* cr = &cs[d * 32];
        float s = 0.f;
        #pragma unroll
        for (int e4 = 0; e4 < 8; ++e4) {
            f32x4 t = *(const f32x4*)&cr[e4 * 4];
            s += w[e4 * 4] * t[0] + w[e4 * 4 + 1] * t[1]
               + w[e4 * 4 + 2] * t[2] + w[e4 * 4 + 3] * t[3];
        }
        val[dd] = s * SCALE / ses[d];
    }
    unsigned* wm32 = (unsigned*)wmod;
    size_t base = (size_t)(b * CH + c) * 64 + h * 16 + (d0 >> 1);
    #pragma unroll
    for (int i = 0; i < 8; ++i)
        wm32[base + i] = (unsigned)f2us(val[2 * i]) | ((unsigned)f2us(val[2 * i + 1]) << 16);
}

// ---------------------------------------------------------------------------
// K3: fused y-GEMM (y[n][c] = sum_hd p[n][hd]*wmod[c][hd] + bout[c]) + channel
// LN + residual -> out fp32. grid (32 n-tiles, 16 b), 256 threads.
// ---------------------------------------------------------------------------
__global__ __launch_bounds__(256)
void fused_out_kernel(const bf16* __restrict__ p, const bf16* __restrict__ wmod,
                      const float* __restrict__ bout, const float* __restrict__ x,
                      float* __restrict__ out) {
    __shared__ char lds[51200];
    bf16* Ap = (bf16*)lds;                 // [128][136] = 34816 B (union: ct)
    bf16* Bw = (bf16*)(lds + 34816);       // [256][32]  = 16384 B
    float* ct = (float*)lds;               // [256][33] f32 = 33792 B
    float* st = (float*)(lds + 34816);     // stats

    const int b = blockIdx.y, n0 = blockIdx.x * 128;
    const int tid = threadIdx.x;
    const int wave = tid >> 6, lane = tid & 63;
    const int wm = (wave >> 1) * 64, wn2 = (wave & 1) * 128;
    const int lrow = lane & 15, kq = lane >> 4;

    {
        const unsigned* pg32 = (const unsigned*)p;
        unsigned* A32 = (unsigned*)Ap;
        #pragma unroll 4
        for (int i = 0; i < 32; ++i) {
            int idx = i * 256 + tid;
            int c2 = idx & 63, n = idx >> 6;
            A32[n * 68 + c2] = pg32[(size_t)(b * NPOS + n0 + n) * 64 + c2];
        }
    }

    f32x4 acc[4][8];
    #pragma unroll
    for (int i = 0; i < 4; ++i)
        #pragma unroll
        for (int j = 0; j < 8; ++j) acc[i][j] = (f32x4){0.f, 0.f, 0.f, 0.f};

    const bf16* wb = wmod + (size_t)b * CH * INNER;
    for (int k0 = 0; k0 < 128; k0 += 32) {
        __syncthreads();
        #pragma unroll
        for (int i = 0; i < 4; ++i) {
            int s = i * 256 + tid;
            int col = s >> 2, q4 = s & 3;
            uint4 u = *(const uint4*)&wb[(size_t)col * 128 + k0 + q4 * 8];
            *(uint4*)&Bw[col * 32 + q4 * 8] = u;
        }
        __syncthreads();
        bf8v af[4], bfr[8];
        #pragma unroll
        for (int t = 0; t < 4; ++t)
            af[t] = *(const bf8v*)&Ap[(wm + t * 16 + lrow) * 136 + k0 + kq * 8];
        #pragma unroll
        for (int t = 0; t < 8; ++t)
            bfr[t] = *(const bf8v*)&Bw[(wn2 + t * 16 + lrow) * 32 + kq * 8];
        #pragma unroll
        for (int mt = 0; mt < 4; ++mt)
            #pragma unroll
            for (int nt = 0; nt < 8; ++nt)
                acc[mt][nt] = __builtin_amdgcn_mfma_f32_16x16x32_bf16(
                    af[mt], bfr[nt], acc[mt][nt], 0, 0, 0);
    }

    #pragma unroll
    for (int nt = 0; nt < 8; ++nt) {
        float bv = bout[wn2 + nt * 16 + lrow];
        #pragma unroll
        for (int mt = 0; mt < 4; ++mt)
            #pragma unroll
            for (int r = 0; r < 4; ++r) acc[mt][nt][r] += bv;
    }

    __syncthreads();
    #pragma unroll
    for (int mt = 0; mt < 4; ++mt)
        #pragma unroll
        for (int r = 0; r < 4; ++r) {
            float s = 0.f, sq = 0.f;
            #pragma unroll
            for (int nt = 0; nt < 8; ++nt) {
                float v = acc[mt][nt][r];
                s += v; sq += v * v;
            }
            #pragma unroll
            for (int m = 1; m <= 8; m <<= 1) {
                s += __shfl_xor(s, m, 64);
                sq += __shfl_xor(sq, m, 64);
            }
            if (lrow == 0) {
                int row = wm + mt * 16 + kq * 4 + r;
                st[(wave & 1) * 256 + row * 2] = s;
                st[(wave & 1) * 256 + row * 2 + 1] = sq;
            }
        }
    __syncthreads();
    if (tid < 128) {
        float s  = st[tid * 2] + st[256 + tid * 2];
        float sq = st[tid * 2 + 1] + st[256 + tid * 2 + 1];
        float m = s * (1.f / 256.f);
        float var = sq * (1.f / 256.f) - m * m;
        st[512 + tid * 2] = m;
        st[512 + tid * 2 + 1] = rsqrtf(var + 1e-5f);
    }
    __syncthreads();
    #pragma unroll
    for (int mt = 0; mt < 4; ++mt)
        #pragma unroll
        for (int r = 0; r < 4; ++r) {
            int row = wm + mt * 16 + kq * 4 + r;
            float m = st[512 + row * 2], rs = st[512 + row * 2 + 1];
            #pragma unroll
            for (int nt = 0; nt < 8; ++nt)
                acc[mt][nt][r] = (acc[mt][nt][r] - m) * rs;
        }

    for (int pr = 0; pr < 4; ++pr) {
        __syncthreads();
        if ((wave >> 1) == (pr >> 1)) {
            int mtb = (pr & 1) * 2;
            #pragma unroll
            for (int mi = 0; mi < 2; ++mi) {
                int mt = mtb + mi;
                #pragma unroll
                for (int nt = 0; nt < 8; ++nt)
                    #pragma unroll
                    for (int r = 0; r < 4; ++r) {
                        int rl = mi * 16 + kq * 4 + r;
                        ct[(wn2 + nt * 16 + lrow) * 33 + rl] = acc[mt][nt][r];
                    }
            }
        }
        __syncthreads();
        #pragma unroll 4
        for (int i = 0; i < 32; ++i) {
            int idx = i * 256 + tid;
            int n = idx & 31, c = idx >> 5;
            size_t gi = ((size_t)b * CH + c) * NPOS + n0 + pr * 32 + n;
            out[gi] = ct[c * 33 + n] + x[gi];
        }
    }
}

// ---------------------------------------------------------------------------
extern "C" void kernel_launch(void* const* d_in, const int* in_sizes, int n_in,
                              void* d_out, int out_size, void* d_ws, size_t ws_size,
                              hipStream_t stream) {
    const float* x    = (const float*)d_in[0];   // [16,256,64,64]
    const float* Wqkv = (const float*)d_in[1];   // [384,256]
    const float* Wout = (const float*)d_in[2];   // [256,128]
    const float* bout = (const float*)d_in[3];   // [256]
    float* out = (float*)d_out;

    // workspace (~51.6 MB)
    char* ws = (char*)d_ws;
    bf16* p    = (bf16*)ws;                      // 16*4096*128*2 = 16777216
    bf16* kvt  = (bf16*)(ws + 16777216);         // 16*4096*256*2 = 33554432
    bf16* wmod = (bf16*)(ws + 50331648);         // 16*256*128*2  = 1048576
    bf16* wq   = (bf16*)(ws + 51380224);         // 384*256*2     = 196608

    convert_wq_kernel<<<96, 256, 0, stream>>>(Wqkv, wq);
    fused_qkv_kernel<<<dim3(32, BATCH), 512, 0, stream>>>(x, wq, p, kvt);
    context_wmod_kernel<<<dim3(HEADS, BATCH), 512, 0, stream>>>(kvt, Wout, wmod);
    fused_out_kernel<<<dim3(32, BATCH), 256, 0, stream>>>(p, wmod, bout, x, out);
}